// Round 1
// baseline (481.491 us; speedup 1.0000x reference)
//
#include <hip/hip_runtime.h>
#include <stdint.h>
#include <stddef.h>

#define DIMN 2048
#define NH 16
#define HD 128
#define SEQ 2048
#define WIN 128   // mask: j - i > 128 is masked

typedef __attribute__((ext_vector_type(4))) float f32x4;
typedef __attribute__((ext_vector_type(8))) short bf16x8;
typedef __attribute__((ext_vector_type(4))) int i32x4;

__device__ __forceinline__ unsigned short f2bf(float f) {
  union { float f; unsigned u; } v; v.f = f;
  unsigned r = v.u + 0x7FFFu + ((v.u >> 16) & 1u);  // round-to-nearest-even
  return (unsigned short)(r >> 16);
}

// ---------------- cast f32 -> bf16 ----------------
__global__ void cast_bf16_kernel(const float* __restrict__ src,
                                 unsigned short* __restrict__ dst, int n4) {
  int i = blockIdx.x * blockDim.x + threadIdx.x;
  const int stride = gridDim.x * blockDim.x;
  for (; i < n4; i += stride) {
    float4 v = ((const float4*)src)[i];
    ushort4 o;
    o.x = f2bf(v.x); o.y = f2bf(v.y); o.z = f2bf(v.z); o.w = f2bf(v.w);
    ((ushort4*)dst)[i] = o;
  }
}

// ---------------- shared GEMM mainloop ----------------
// C(128x128) = A(Mx2048 rowmajor) x B(Nx2048 rowmajor)^T, bf16 in, f32 acc.
// 4 waves in 2x2; each wave owns 64x64 = 4x4 frags of 16x16.
// LDS rows padded to 40 elems (80B = 5*16B, odd 16B-slot stride -> conflict-spread).
__device__ __forceinline__ void gemm_mainloop_128(
    const unsigned short* __restrict__ A, const unsigned short* __restrict__ B,
    int m0, int n0,
    unsigned short (*As)[40], unsigned short (*Bs)[40],
    f32x4 acc[4][4]) {
  const int t = threadIdx.x;
  const int lane = t & 63, wid = t >> 6;
  const int c = lane & 15, g = lane >> 4;
  const int wr = wid >> 1, wc = wid & 1;
  const int sr = t >> 2;          // staging row 0..63
  const int sc8 = (t & 3) * 8;    // staging col offset (elems)

  const unsigned short* pa0 = A + (size_t)(m0 + sr) * DIMN + sc8;
  const unsigned short* pa1 = pa0 + (size_t)64 * DIMN;
  const unsigned short* pb0 = B + (size_t)(n0 + sr) * DIMN + sc8;
  const unsigned short* pb1 = pb0 + (size_t)64 * DIMN;

  i32x4 ra0 = *(const i32x4*)pa0;
  i32x4 ra1 = *(const i32x4*)pa1;
  i32x4 rb0 = *(const i32x4*)pb0;
  i32x4 rb1 = *(const i32x4*)pb1;

  for (int k0 = 0; k0 < DIMN; k0 += 32) {
    __syncthreads();  // previous tile's readers done
    *(i32x4*)&As[sr][sc8] = ra0;
    *(i32x4*)&As[sr + 64][sc8] = ra1;
    *(i32x4*)&Bs[sr][sc8] = rb0;
    *(i32x4*)&Bs[sr + 64][sc8] = rb1;
    __syncthreads();
    if (k0 + 32 < DIMN) {  // prefetch next K-step into regs (overlaps MFMA below)
      ra0 = *(const i32x4*)(pa0 + k0 + 32);
      ra1 = *(const i32x4*)(pa1 + k0 + 32);
      rb0 = *(const i32x4*)(pb0 + k0 + 32);
      rb1 = *(const i32x4*)(pb1 + k0 + 32);
    }
    bf16x8 af[4], bfv[4];
#pragma unroll
    for (int mi = 0; mi < 4; ++mi)
      af[mi] = *(const bf16x8*)&As[wr * 64 + mi * 16 + c][g * 8];
#pragma unroll
    for (int ni = 0; ni < 4; ++ni)
      bfv[ni] = *(const bf16x8*)&Bs[wc * 64 + ni * 16 + c][g * 8];
#pragma unroll
    for (int mi = 0; mi < 4; ++mi)
#pragma unroll
      for (int ni = 0; ni < 4; ++ni)
        acc[mi][ni] = __builtin_amdgcn_mfma_f32_16x16x32_bf16(
            af[mi], bfv[ni], acc[mi][ni], 0, 0, 0);
  }
}

// ---------------- QKV projection (z: 0=Q, 1=K, 2=V-transposed) ----------------
__global__ __launch_bounds__(256, 2) void gemm_qkv_kernel(
    const unsigned short* __restrict__ Xb,
    const unsigned short* __restrict__ Wq,
    const unsigned short* __restrict__ Wk,
    const unsigned short* __restrict__ Wv,
    unsigned short* __restrict__ Qb,
    unsigned short* __restrict__ Kb,
    unsigned short* __restrict__ Vt) {
  __shared__ __attribute__((aligned(16))) unsigned short As[128][40];
  __shared__ __attribute__((aligned(16))) unsigned short Bs[128][40];
  const int z = blockIdx.z;
  const unsigned short* W = (z == 0) ? Wq : (z == 1) ? Wk : Wv;
  const int m0 = blockIdx.y * 128, n0 = blockIdx.x * 128;

  f32x4 acc[4][4];
  const f32x4 zv = {0.f, 0.f, 0.f, 0.f};
#pragma unroll
  for (int i = 0; i < 4; ++i)
#pragma unroll
    for (int j = 0; j < 4; ++j) acc[i][j] = zv;

  gemm_mainloop_128(Xb, W, m0, n0, As, Bs, acc);

  const int lane = threadIdx.x & 63, wid = threadIdx.x >> 6;
  const int c = lane & 15, g = lane >> 4;
  const int wr = wid >> 1, wc = wid & 1;
  unsigned short* Out01 = (z == 0) ? Qb : Kb;
#pragma unroll
  for (int mi = 0; mi < 4; ++mi) {
#pragma unroll
    for (int ni = 0; ni < 4; ++ni) {
      const int mrow = m0 + wr * 64 + mi * 16 + g * 4;  // m = b*SEQ + s, mrow%4==0
      const int ncol = n0 + wc * 64 + ni * 16 + c;      // n = h*HD + d
      const int h = ncol >> 7, d = ncol & 127;
      const int b = mrow >> 11, s = mrow & 2047;
      if (z < 2) {
        // (B,H,S,D) bf16
#pragma unroll
        for (int j = 0; j < 4; ++j)
          Out01[((size_t)(b * NH + h) * SEQ + s + j) * HD + d] =
              f2bf(acc[mi][ni][j]);
      } else {
        // V stored transposed: (B,H,D,S) bf16 — 4 consecutive s pack to 8B
        ushort4 pk;
        pk.x = f2bf(acc[mi][ni][0]); pk.y = f2bf(acc[mi][ni][1]);
        pk.z = f2bf(acc[mi][ni][2]); pk.w = f2bf(acc[mi][ni][3]);
        *(ushort4*)&Vt[((size_t)(b * NH + h) * HD + d) * SEQ + s] = pk;
      }
    }
  }
}

// ---------------- output projection: f32 out ----------------
__global__ __launch_bounds__(256, 2) void gemm_out_kernel(
    const unsigned short* __restrict__ Ab,
    const unsigned short* __restrict__ Wo,
    float* __restrict__ Cf) {
  __shared__ __attribute__((aligned(16))) unsigned short As[128][40];
  __shared__ __attribute__((aligned(16))) unsigned short Bs[128][40];
  const int m0 = blockIdx.y * 128, n0 = blockIdx.x * 128;

  f32x4 acc[4][4];
  const f32x4 zv = {0.f, 0.f, 0.f, 0.f};
#pragma unroll
  for (int i = 0; i < 4; ++i)
#pragma unroll
    for (int j = 0; j < 4; ++j) acc[i][j] = zv;

  gemm_mainloop_128(Ab, Wo, m0, n0, As, Bs, acc);

  const int lane = threadIdx.x & 63, wid = threadIdx.x >> 6;
  const int c = lane & 15, g = lane >> 4;
  const int wr = wid >> 1, wc = wid & 1;
#pragma unroll
  for (int mi = 0; mi < 4; ++mi) {
#pragma unroll
    for (int ni = 0; ni < 4; ++ni) {
      const int mrow = m0 + wr * 64 + mi * 16 + g * 4;
      const int ncol = n0 + wc * 64 + ni * 16 + c;
#pragma unroll
      for (int j = 0; j < 4; ++j)
        Cf[(size_t)(mrow + j) * DIMN + ncol] = acc[mi][ni][j];
    }
  }
}

// ---------------- flash attention, mask j <= i+128 ----------------
// Block: 64 q-rows of one (b,h); 4 waves x 16 rows. KV tile = 64.
// Q in regs; K (64x128) and V^T (128x64) staged in padded LDS; P via per-wave LDS.
__global__ __launch_bounds__(256, 2) void attn_kernel(
    const unsigned short* __restrict__ Qg,
    const unsigned short* __restrict__ Kg,
    const unsigned short* __restrict__ Vtg,
    unsigned short* __restrict__ Og) {
  __shared__ __attribute__((aligned(16))) unsigned short Ks[64][136];   // 272B rows (17*16B)
  __shared__ __attribute__((aligned(16))) unsigned short Vs[128][72];   // 144B rows (9*16B)
  __shared__ __attribute__((aligned(16))) unsigned short Ps[4][16][72]; // per-wave P

  const int qt = blockIdx.x, bh = blockIdx.y;
  const int q0 = qt * 64;
  const int t = threadIdx.x, wid = t >> 6, lane = t & 63;
  const int c = lane & 15, g = lane >> 4;

  // Q fragments for this wave's 16 rows (A-operand: row=c, k = kk*32 + g*8 + 0..7)
  const unsigned short* qbase =
      Qg + ((size_t)bh * SEQ + q0 + wid * 16 + c) * HD + g * 8;
  bf16x8 qf[4];
#pragma unroll
  for (int kk = 0; kk < 4; ++kk) qf[kk] = *(const bf16x8*)(qbase + kk * 32);

  f32x4 o[8];
  const f32x4 zv = {0.f, 0.f, 0.f, 0.f};
#pragma unroll
  for (int ni = 0; ni < 8; ++ni) o[ni] = zv;
  float M[4], L[4];
#pragma unroll
  for (int j = 0; j < 4; ++j) { M[j] = -1e30f; L[j] = 0.f; }

  const int jmax = (q0 + 192 < SEQ) ? (q0 + 192) : SEQ;  // keys [0, q0+192)
  const int nt = jmax >> 6;
  const float kl2e = 0.08838834764831845f * 1.4426950408889634f;  // scale*log2(e)

  const unsigned short* Kbh = Kg + (size_t)bh * SEQ * HD;
  const unsigned short* Vbh = Vtg + (size_t)bh * HD * SEQ;

  i32x4 kc[4], vc[4];
#pragma unroll
  for (int r = 0; r < 4; ++r) {  // prologue: tile 0
    const int qq = t + r * 256;
    kc[r] = *(const i32x4*)(Kbh + (size_t)(qq >> 4) * HD + (qq & 15) * 8);
    vc[r] = *(const i32x4*)(Vbh + (size_t)(qq >> 3) * SEQ + (qq & 7) * 8);
  }

  for (int tt = 0; tt < nt; ++tt) {
    const int j0 = tt * 64;
    __syncthreads();  // previous tile's MFMA reads done
#pragma unroll
    for (int r = 0; r < 4; ++r) {
      const int qq = t + r * 256;
      *(i32x4*)&Ks[qq >> 4][(qq & 15) * 8] = kc[r];
      *(i32x4*)&Vs[qq >> 3][(qq & 7) * 8] = vc[r];
    }
    __syncthreads();
    if (tt + 1 < nt) {  // prefetch next tile into regs; latency hides under compute
      const int j1 = j0 + 64;
#pragma unroll
      for (int r = 0; r < 4; ++r) {
        const int qq = t + r * 256;
        kc[r] = *(const i32x4*)(Kbh + (size_t)(j1 + (qq >> 4)) * HD + (qq & 15) * 8);
        vc[r] = *(const i32x4*)(Vbh + (size_t)(qq >> 3) * SEQ + j1 + (qq & 7) * 8);
      }
    }

    // QK^T: 16 rows x 64 cols; sc[ni] holds rows 4g+j, col 16ni+c
    f32x4 sc[4];
#pragma unroll
    for (int ni = 0; ni < 4; ++ni) sc[ni] = zv;
#pragma unroll
    for (int kk = 0; kk < 4; ++kk) {
#pragma unroll
      for (int ni = 0; ni < 4; ++ni) {
        const bf16x8 kf = *(const bf16x8*)&Ks[ni * 16 + c][kk * 32 + g * 8];
        sc[ni] = __builtin_amdgcn_mfma_f32_16x16x32_bf16(qf[kk], kf, sc[ni], 0, 0, 0);
      }
    }

    // only the tile at j0 = q0+128 can contain masked elements
    if (j0 - q0 == 128) {
#pragma unroll
      for (int ni = 0; ni < 4; ++ni) {
        const int jg = j0 + ni * 16 + c;
#pragma unroll
        for (int j = 0; j < 4; ++j) {
          const int ig = q0 + wid * 16 + g * 4 + j;
          if (jg > ig + WIN) sc[ni][j] = -3.0e38f;
        }
      }
    }

    // online softmax (rows 4g+j live in the 16-lane group sharing g)
    float al[4];
#pragma unroll
    for (int j = 0; j < 4; ++j) {
      float mx = fmaxf(fmaxf(sc[0][j], sc[1][j]), fmaxf(sc[2][j], sc[3][j]));
      mx = fmaxf(mx, __shfl_xor(mx, 1));
      mx = fmaxf(mx, __shfl_xor(mx, 2));
      mx = fmaxf(mx, __shfl_xor(mx, 4));
      mx = fmaxf(mx, __shfl_xor(mx, 8));
      const float nm = fmaxf(M[j], mx);
      al[j] = __builtin_amdgcn_exp2f((M[j] - nm) * kl2e);
      M[j] = nm;
    }

    float rs[4] = {0.f, 0.f, 0.f, 0.f};
#pragma unroll
    for (int ni = 0; ni < 4; ++ni) {
#pragma unroll
      for (int j = 0; j < 4; ++j) {
        const float p = __builtin_amdgcn_exp2f((sc[ni][j] - M[j]) * kl2e);
        rs[j] += p;
        Ps[wid][g * 4 + j][ni * 16 + c] = f2bf(p);  // transpose via per-wave LDS
      }
    }
#pragma unroll
    for (int j = 0; j < 4; ++j) {
      float s = rs[j];
      s += __shfl_xor(s, 1);
      s += __shfl_xor(s, 2);
      s += __shfl_xor(s, 4);
      s += __shfl_xor(s, 8);
      L[j] = L[j] * al[j] + s;
#pragma unroll
      for (int ni = 0; ni < 8; ++ni) o[ni][j] *= al[j];
    }

    // PV: P(16x64) * V(64x128); V^T rows are d, contiguous in s
#pragma unroll
    for (int kk2 = 0; kk2 < 2; ++kk2) {
      const bf16x8 pf = *(const bf16x8*)&Ps[wid][c][kk2 * 32 + g * 8];
#pragma unroll
      for (int ni = 0; ni < 8; ++ni) {
        const bf16x8 vf = *(const bf16x8*)&Vs[ni * 16 + c][kk2 * 32 + g * 8];
        o[ni] = __builtin_amdgcn_mfma_f32_16x16x32_bf16(pf, vf, o[ni], 0, 0, 0);
      }
    }
  }

  // normalize + store attn output as (B*S, DIM) bf16 rows (GEMM2 A-operand)
  const int b = bh >> 4, h = bh & 15;
#pragma unroll
  for (int j = 0; j < 4; ++j) {
    const float inv = 1.0f / L[j];
    const int s = q0 + wid * 16 + g * 4 + j;
    unsigned short* orow = Og + (size_t)(b * SEQ + s) * DIMN + h * HD;
#pragma unroll
    for (int ni = 0; ni < 8; ++ni) orow[ni * 16 + c] = f2bf(o[ni][j] * inv);
  }
}

// ---------------- launch ----------------
extern "C" void kernel_launch(void* const* d_in, const int* in_sizes, int n_in,
                              void* d_out, int out_size, void* d_ws, size_t ws_size,
                              hipStream_t stream) {
  (void)in_sizes; (void)n_in; (void)out_size; (void)ws_size;
  const float* x  = (const float*)d_in[0];
  const float* wq = (const float*)d_in[1];
  const float* wk = (const float*)d_in[2];
  const float* wv = (const float*)d_in[3];
  const float* wo = (const float*)d_in[4];
  float* out = (float*)d_out;

  // workspace layout (bf16 elems); total ~112 MB
  unsigned short* xb  = (unsigned short*)d_ws;          // 4096x2048
  unsigned short* wqb = xb  + (size_t)8388608;          // 2048x2048 each
  unsigned short* wkb = wqb + (size_t)4194304;
  unsigned short* wvb = wkb + (size_t)4194304;
  unsigned short* wob = wvb + (size_t)4194304;
  unsigned short* Qb  = wob + (size_t)4194304;          // (B,H,S,D)
  unsigned short* Kb  = Qb  + (size_t)8388608;          // (B,H,S,D)
  unsigned short* Vt  = Kb  + (size_t)8388608;          // (B,H,D,S)
  unsigned short* Ab  = Vt  + (size_t)8388608;          // (B*S, DIM)

  cast_bf16_kernel<<<dim3(1024), dim3(256), 0, stream>>>(x,  xb,  2097152);
  cast_bf16_kernel<<<dim3(512),  dim3(256), 0, stream>>>(wq, wqb, 1048576);
  cast_bf16_kernel<<<dim3(512),  dim3(256), 0, stream>>>(wk, wkb, 1048576);
  cast_bf16_kernel<<<dim3(512),  dim3(256), 0, stream>>>(wv, wvb, 1048576);
  cast_bf16_kernel<<<dim3(512),  dim3(256), 0, stream>>>(wo, wob, 1048576);

  gemm_qkv_kernel<<<dim3(16, 32, 3), dim3(256), 0, stream>>>(xb, wqb, wkb, wvb, Qb, Kb, Vt);
  attn_kernel<<<dim3(32, 32), dim3(256), 0, stream>>>(Qb, Kb, Vt, Ab);
  gemm_out_kernel<<<dim3(16, 32), dim3(256), 0, stream>>>(Ab, wob, out);
}

// Round 2
// 417.369 us; speedup vs baseline: 1.1536x; 1.1536x over previous
//
#include <hip/hip_runtime.h>
#include <stdint.h>
#include <stddef.h>

#define DIMN 2048
#define NH 16
#define HD 128
#define SEQ 2048
#define WIN 128   // mask: j - i > 128 is masked

typedef __attribute__((ext_vector_type(4))) float f32x4;
typedef __attribute__((ext_vector_type(8))) short bf16x8;
typedef __attribute__((ext_vector_type(4))) int i32x4;

__device__ __forceinline__ unsigned short f2bf(float f) {
  union { float f; unsigned u; } v; v.f = f;
  unsigned r = v.u + 0x7FFFu + ((v.u >> 16) & 1u);  // round-to-nearest-even
  return (unsigned short)(r >> 16);
}

// ---------------- cast f32 -> bf16 ----------------
__global__ void cast_bf16_kernel(const float* __restrict__ src,
                                 unsigned short* __restrict__ dst, int n4) {
  int i = blockIdx.x * blockDim.x + threadIdx.x;
  const int stride = gridDim.x * blockDim.x;
  for (; i < n4; i += stride) {
    float4 v = ((const float4*)src)[i];
    ushort4 o;
    o.x = f2bf(v.x); o.y = f2bf(v.y); o.z = f2bf(v.z); o.w = f2bf(v.w);
    ((ushort4*)dst)[i] = o;
  }
}

// fused cast of the 4 weight matrices (dst regions contiguous in ws)
__global__ void cast4_bf16_kernel(const float* __restrict__ s0, const float* __restrict__ s1,
                                  const float* __restrict__ s2, const float* __restrict__ s3,
                                  unsigned short* __restrict__ dst, int n4) {
  const float* s = (blockIdx.y == 0) ? s0 : (blockIdx.y == 1) ? s1 : (blockIdx.y == 2) ? s2 : s3;
  unsigned short* d = dst + (size_t)blockIdx.y * 4194304;
  int i = blockIdx.x * blockDim.x + threadIdx.x;
  const int stride = gridDim.x * blockDim.x;
  for (; i < n4; i += stride) {
    float4 v = ((const float4*)s)[i];
    ushort4 o;
    o.x = f2bf(v.x); o.y = f2bf(v.y); o.z = f2bf(v.z); o.w = f2bf(v.w);
    ((ushort4*)d)[i] = o;
  }
}

// ---------------- shared GEMM mainloop (unchanged — not the bottleneck) ----------------
__device__ __forceinline__ void gemm_mainloop_128(
    const unsigned short* __restrict__ A, const unsigned short* __restrict__ B,
    int m0, int n0,
    unsigned short (*As)[40], unsigned short (*Bs)[40],
    f32x4 acc[4][4]) {
  const int t = threadIdx.x;
  const int lane = t & 63, wid = t >> 6;
  const int c = lane & 15, g = lane >> 4;
  const int wr = wid >> 1, wc = wid & 1;
  const int sr = t >> 2;          // staging row 0..63
  const int sc8 = (t & 3) * 8;    // staging col offset (elems)

  const unsigned short* pa0 = A + (size_t)(m0 + sr) * DIMN + sc8;
  const unsigned short* pa1 = pa0 + (size_t)64 * DIMN;
  const unsigned short* pb0 = B + (size_t)(n0 + sr) * DIMN + sc8;
  const unsigned short* pb1 = pb0 + (size_t)64 * DIMN;

  i32x4 ra0 = *(const i32x4*)pa0;
  i32x4 ra1 = *(const i32x4*)pa1;
  i32x4 rb0 = *(const i32x4*)pb0;
  i32x4 rb1 = *(const i32x4*)pb1;

  for (int k0 = 0; k0 < DIMN; k0 += 32) {
    __syncthreads();  // previous tile's readers done
    *(i32x4*)&As[sr][sc8] = ra0;
    *(i32x4*)&As[sr + 64][sc8] = ra1;
    *(i32x4*)&Bs[sr][sc8] = rb0;
    *(i32x4*)&Bs[sr + 64][sc8] = rb1;
    __syncthreads();
    if (k0 + 32 < DIMN) {  // prefetch next K-step into regs (overlaps MFMA below)
      ra0 = *(const i32x4*)(pa0 + k0 + 32);
      ra1 = *(const i32x4*)(pa1 + k0 + 32);
      rb0 = *(const i32x4*)(pb0 + k0 + 32);
      rb1 = *(const i32x4*)(pb1 + k0 + 32);
    }
    bf16x8 af[4], bfv[4];
#pragma unroll
    for (int mi = 0; mi < 4; ++mi)
      af[mi] = *(const bf16x8*)&As[wr * 64 + mi * 16 + c][g * 8];
#pragma unroll
    for (int ni = 0; ni < 4; ++ni)
      bfv[ni] = *(const bf16x8*)&Bs[wc * 64 + ni * 16 + c][g * 8];
#pragma unroll
    for (int mi = 0; mi < 4; ++mi)
#pragma unroll
      for (int ni = 0; ni < 4; ++ni)
        acc[mi][ni] = __builtin_amdgcn_mfma_f32_16x16x32_bf16(
            af[mi], bfv[ni], acc[mi][ni], 0, 0, 0);
  }
}

// ---------------- QKV projection (z: 0=Q, 1=K, 2=V-transposed) ----------------
__global__ __launch_bounds__(256, 2) void gemm_qkv_kernel(
    const unsigned short* __restrict__ Xb,
    const unsigned short* __restrict__ Wq,
    const unsigned short* __restrict__ Wk,
    const unsigned short* __restrict__ Wv,
    unsigned short* __restrict__ Qb,
    unsigned short* __restrict__ Kb,
    unsigned short* __restrict__ Vt) {
  __shared__ __attribute__((aligned(16))) unsigned short As[128][40];
  __shared__ __attribute__((aligned(16))) unsigned short Bs[128][40];
  const int z = blockIdx.z;
  const unsigned short* W = (z == 0) ? Wq : (z == 1) ? Wk : Wv;
  const int m0 = blockIdx.y * 128, n0 = blockIdx.x * 128;

  f32x4 acc[4][4];
  const f32x4 zv = {0.f, 0.f, 0.f, 0.f};
#pragma unroll
  for (int i = 0; i < 4; ++i)
#pragma unroll
    for (int j = 0; j < 4; ++j) acc[i][j] = zv;

  gemm_mainloop_128(Xb, W, m0, n0, As, Bs, acc);

  const int lane = threadIdx.x & 63, wid = threadIdx.x >> 6;
  const int c = lane & 15, g = lane >> 4;
  const int wr = wid >> 1, wc = wid & 1;
  unsigned short* Out01 = (z == 0) ? Qb : Kb;
#pragma unroll
  for (int mi = 0; mi < 4; ++mi) {
#pragma unroll
    for (int ni = 0; ni < 4; ++ni) {
      const int mrow = m0 + wr * 64 + mi * 16 + g * 4;  // m = b*SEQ + s, mrow%4==0
      const int ncol = n0 + wc * 64 + ni * 16 + c;      // n = h*HD + d
      const int h = ncol >> 7, d = ncol & 127;
      const int b = mrow >> 11, s = mrow & 2047;
      if (z < 2) {
#pragma unroll
        for (int j = 0; j < 4; ++j)
          Out01[((size_t)(b * NH + h) * SEQ + s + j) * HD + d] =
              f2bf(acc[mi][ni][j]);
      } else {
        ushort4 pk;
        pk.x = f2bf(acc[mi][ni][0]); pk.y = f2bf(acc[mi][ni][1]);
        pk.z = f2bf(acc[mi][ni][2]); pk.w = f2bf(acc[mi][ni][3]);
        *(ushort4*)&Vt[((size_t)(b * NH + h) * HD + d) * SEQ + s] = pk;
      }
    }
  }
}

// ---------------- output projection: f32 out ----------------
__global__ __launch_bounds__(256, 2) void gemm_out_kernel(
    const unsigned short* __restrict__ Ab,
    const unsigned short* __restrict__ Wo,
    float* __restrict__ Cf) {
  __shared__ __attribute__((aligned(16))) unsigned short As[128][40];
  __shared__ __attribute__((aligned(16))) unsigned short Bs[128][40];
  const int m0 = blockIdx.y * 128, n0 = blockIdx.x * 128;

  f32x4 acc[4][4];
  const f32x4 zv = {0.f, 0.f, 0.f, 0.f};
#pragma unroll
  for (int i = 0; i < 4; ++i)
#pragma unroll
    for (int j = 0; j < 4; ++j) acc[i][j] = zv;

  gemm_mainloop_128(Ab, Wo, m0, n0, As, Bs, acc);

  const int lane = threadIdx.x & 63, wid = threadIdx.x >> 6;
  const int c = lane & 15, g = lane >> 4;
  const int wr = wid >> 1, wc = wid & 1;
#pragma unroll
  for (int mi = 0; mi < 4; ++mi) {
#pragma unroll
    for (int ni = 0; ni < 4; ++ni) {
      const int mrow = m0 + wr * 64 + mi * 16 + g * 4;
      const int ncol = n0 + wc * 64 + ni * 16 + c;
#pragma unroll
      for (int j = 0; j < 4; ++j)
        Cf[(size_t)(mrow + j) * DIMN + ncol] = acc[mi][ni][j];
    }
  }
}

// ---------------- flash attention v2 ----------------
// 128 q-rows per block (4 waves x 32 rows), KV tile = 64.
// K[64][128], V^T[128][64], P[4][32][64] in LDS, all XOR-slot-swizzled
// (slot' = slot ^ (row&7), 16B slots) -> 2-way bank access (free).
// Grid: (x=bh=32, y=qt=16) so each CU mixes light+heavy q-tiles.
__global__ __launch_bounds__(256, 2) void attn_kernel(
    const unsigned short* __restrict__ Qg,
    const unsigned short* __restrict__ Kg,
    const unsigned short* __restrict__ Vtg,
    unsigned short* __restrict__ Og) {
  __shared__ __attribute__((aligned(16))) unsigned short Ks[64 * 128];
  __shared__ __attribute__((aligned(16))) unsigned short Vs[128 * 64];
  __shared__ __attribute__((aligned(16))) unsigned short Ps[4 * 32 * 64];

  const int bh = blockIdx.x, qt = blockIdx.y;
  const int q0 = qt * 128;
  const int t = threadIdx.x, wid = t >> 6, lane = t & 63;
  const int c = lane & 15, g = lane >> 4;
  const int swc = c & 7;  // swizzle key for reads (row&7 == c&7 for our rows)

  const unsigned short* Kbh = Kg + (size_t)bh * SEQ * HD;
  const unsigned short* Vbh = Vtg + (size_t)bh * HD * SEQ;

  // Q fragments: rows q0 + wid*32 + mi*16 + c ; k = kk*32 + g*8
  bf16x8 qf[2][4];
#pragma unroll
  for (int mi = 0; mi < 2; ++mi) {
    const unsigned short* qb =
        Qg + ((size_t)bh * SEQ + q0 + wid * 32 + mi * 16 + c) * HD + g * 8;
#pragma unroll
    for (int kk = 0; kk < 4; ++kk) qf[mi][kk] = *(const bf16x8*)(qb + kk * 32);
  }

  f32x4 o[2][8];
  const f32x4 zv = {0.f, 0.f, 0.f, 0.f};
#pragma unroll
  for (int mi = 0; mi < 2; ++mi)
#pragma unroll
    for (int ni = 0; ni < 8; ++ni) o[mi][ni] = zv;
  float M[2][4], L[2][4];
#pragma unroll
  for (int mi = 0; mi < 2; ++mi)
#pragma unroll
    for (int j = 0; j < 4; ++j) { M[mi][j] = -1e30f; L[mi][j] = 0.f; }

  const int ntA = (q0 + 256) >> 6;
  const int nt = (ntA < (SEQ >> 6)) ? ntA : (SEQ >> 6);
  const float kl2e = 0.08838834764831845f * 1.4426950408889634f;  // scale*log2(e)

  // staging geometry (per thread, loop-invariant)
  const int kswz = (t & 15) ^ ((t >> 4) & 7);
  const int vswz = (t & 7) ^ ((t >> 3) & 7);
  const int kgo = (t >> 4) * HD + (t & 15) * 8;            // K global offset within tile
  const int klo = (t >> 4) * 128 + kswz * 8;               // K LDS offset
  const int vlo = (t >> 3) * 64 + vswz * 8;                // V LDS offset
  const size_t vgo = (size_t)(t >> 3) * SEQ + (t & 7) * 8; // V global offset

  i32x4 kc[4], vc[4];
#pragma unroll
  for (int r = 0; r < 4; ++r) {  // prologue: tile 0
    kc[r] = *(const i32x4*)(Kbh + (size_t)r * 16 * HD + kgo);
    vc[r] = *(const i32x4*)(Vbh + (size_t)r * 32 * SEQ + vgo);
  }

  for (int tt = 0; tt < nt; ++tt) {
    const int j0 = tt * 64;
    __syncthreads();  // previous tile's LDS readers done
#pragma unroll
    for (int r = 0; r < 4; ++r) {
      *(i32x4*)&Ks[r * 2048 + klo] = kc[r];
      *(i32x4*)&Vs[r * 2048 + vlo] = vc[r];
    }
    __syncthreads();
    if (tt + 1 < nt) {  // prefetch next tile (latency hides under compute)
      const int j1 = j0 + 64;
#pragma unroll
      for (int r = 0; r < 4; ++r) {
        kc[r] = *(const i32x4*)(Kbh + (size_t)(j1 + r * 16) * HD + kgo);
        vc[r] = *(const i32x4*)(Vbh + (size_t)r * 32 * SEQ + j1 + vgo);
      }
    }

    // QK^T: 32 rows x 64 cols per wave; sc[mi][ni]: rows mi*16+4g+j, col 16ni+c
    f32x4 sc[2][4];
#pragma unroll
    for (int mi = 0; mi < 2; ++mi)
#pragma unroll
      for (int ni = 0; ni < 4; ++ni) sc[mi][ni] = zv;
#pragma unroll
    for (int kk = 0; kk < 4; ++kk) {
#pragma unroll
      for (int ni = 0; ni < 4; ++ni) {
        const bf16x8 kf =
            *(const bf16x8*)&Ks[(ni * 16 + c) * 128 + ((kk * 4 + g) ^ swc) * 8];
        sc[0][ni] = __builtin_amdgcn_mfma_f32_16x16x32_bf16(qf[0][kk], kf, sc[0][ni], 0, 0, 0);
        sc[1][ni] = __builtin_amdgcn_mfma_f32_16x16x32_bf16(qf[1][kk], kf, sc[1][ni], 0, 0, 0);
      }
    }

    // masking: only tiles with j0 >= q0+128 can contain masked elements
    if (j0 - q0 >= 128) {
#pragma unroll
      for (int mi = 0; mi < 2; ++mi)
#pragma unroll
        for (int ni = 0; ni < 4; ++ni) {
          const int jg = j0 + ni * 16 + c;
#pragma unroll
          for (int j = 0; j < 4; ++j) {
            const int ig = q0 + wid * 32 + mi * 16 + g * 4 + j;
            if (jg > ig + WIN) sc[mi][ni][j] = -3.0e38f;
          }
        }
    }

    // row maxima (rows live in 16-lane groups sharing g; xor<16 stays in group)
    float tmax[2][4], dmax = -3.0e38f;
#pragma unroll
    for (int mi = 0; mi < 2; ++mi)
#pragma unroll
      for (int j = 0; j < 4; ++j) {
        float mx = fmaxf(fmaxf(sc[mi][0][j], sc[mi][1][j]),
                         fmaxf(sc[mi][2][j], sc[mi][3][j]));
        mx = fmaxf(mx, __shfl_xor(mx, 1));
        mx = fmaxf(mx, __shfl_xor(mx, 2));
        mx = fmaxf(mx, __shfl_xor(mx, 4));
        mx = fmaxf(mx, __shfl_xor(mx, 8));
        tmax[mi][j] = mx;
        dmax = fmaxf(dmax, mx - M[mi][j]);
      }
    // defer-max (T13): rescale only when tile max exceeds running max by >64
    // unscaled logits (64*scale*log2e = 8.2 -> P <= 2^8.2, safe in bf16/f32)
    if (__any(dmax > 64.f)) {
#pragma unroll
      for (int mi = 0; mi < 2; ++mi)
#pragma unroll
        for (int j = 0; j < 4; ++j) {
          const float nm = fmaxf(M[mi][j], tmax[mi][j]);
          const float al = __builtin_amdgcn_exp2f((M[mi][j] - nm) * kl2e);
          M[mi][j] = nm;
          L[mi][j] *= al;
#pragma unroll
          for (int ni = 0; ni < 8; ++ni) o[mi][ni][j] *= al;
        }
    }

    // P = exp(sc - M), bf16, swizzled into per-wave LDS; accumulate row sums
    float rs[2][4] = {{0.f, 0.f, 0.f, 0.f}, {0.f, 0.f, 0.f, 0.f}};
#pragma unroll
    for (int mi = 0; mi < 2; ++mi)
#pragma unroll
      for (int ni = 0; ni < 4; ++ni)
#pragma unroll
        for (int j = 0; j < 4; ++j) {
          const float p = __builtin_amdgcn_exp2f((sc[mi][ni][j] - M[mi][j]) * kl2e);
          rs[mi][j] += p;
          const int prow = mi * 16 + g * 4 + j;
          Ps[wid * 2048 + prow * 64 + ((2 * ni + (c >> 3)) ^ (prow & 7)) * 8 + (c & 7)] =
              f2bf(p);
        }
#pragma unroll
    for (int mi = 0; mi < 2; ++mi)
#pragma unroll
      for (int j = 0; j < 4; ++j) {
        float s = rs[mi][j];
        s += __shfl_xor(s, 1);
        s += __shfl_xor(s, 2);
        s += __shfl_xor(s, 4);
        s += __shfl_xor(s, 8);
        L[mi][j] += s;
      }

    // PV: P(32x64) x V^T ; per-wave Ps, no barrier needed (same-wave write/read)
#pragma unroll
    for (int kk2 = 0; kk2 < 2; ++kk2) {
      bf16x8 pf[2];
#pragma unroll
      for (int mi = 0; mi < 2; ++mi)
        pf[mi] = *(const bf16x8*)&Ps[wid * 2048 + (mi * 16 + c) * 64 +
                                     ((kk2 * 4 + g) ^ swc) * 8];
#pragma unroll
      for (int ni = 0; ni < 8; ++ni) {
        const bf16x8 vf =
            *(const bf16x8*)&Vs[(ni * 16 + c) * 64 + ((kk2 * 4 + g) ^ swc) * 8];
        o[0][ni] = __builtin_amdgcn_mfma_f32_16x16x32_bf16(pf[0], vf, o[0][ni], 0, 0, 0);
        o[1][ni] = __builtin_amdgcn_mfma_f32_16x16x32_bf16(pf[1], vf, o[1][ni], 0, 0, 0);
      }
    }
  }

  // normalize + store attn output as (B*S, DIM) bf16 rows (GEMM2 A-operand)
  const int b = bh >> 4, h = bh & 15;
#pragma unroll
  for (int mi = 0; mi < 2; ++mi)
#pragma unroll
    for (int j = 0; j < 4; ++j) {
      const float inv = 1.0f / L[mi][j];
      const int s = q0 + wid * 32 + mi * 16 + g * 4 + j;
      unsigned short* orow = Og + (size_t)(b * SEQ + s) * DIMN + h * HD;
#pragma unroll
      for (int ni = 0; ni < 8; ++ni) orow[ni * 16 + c] = f2bf(o[mi][ni][j] * inv);
    }
}

// ---------------- launch ----------------
extern "C" void kernel_launch(void* const* d_in, const int* in_sizes, int n_in,
                              void* d_out, int out_size, void* d_ws, size_t ws_size,
                              hipStream_t stream) {
  (void)in_sizes; (void)n_in; (void)out_size; (void)ws_size;
  const float* x  = (const float*)d_in[0];
  const float* wq = (const float*)d_in[1];
  const float* wk = (const float*)d_in[2];
  const float* wv = (const float*)d_in[3];
  const float* wo = (const float*)d_in[4];
  float* out = (float*)d_out;

  // workspace layout (bf16 elems); total ~112 MB
  unsigned short* xb  = (unsigned short*)d_ws;          // 4096x2048
  unsigned short* wqb = xb  + (size_t)8388608;          // 2048x2048 each, contiguous
  unsigned short* wkb = wqb + (size_t)4194304;
  unsigned short* wvb = wkb + (size_t)4194304;
  unsigned short* wob = wvb + (size_t)4194304;
  unsigned short* Qb  = wob + (size_t)4194304;          // (B,H,S,D)
  unsigned short* Kb  = Qb  + (size_t)8388608;          // (B,H,S,D)
  unsigned short* Vt  = Kb  + (size_t)8388608;          // (B,H,D,S)
  unsigned short* Ab  = Vt  + (size_t)8388608;          // (B*S, DIM)

  cast_bf16_kernel<<<dim3(1024), dim3(256), 0, stream>>>(x, xb, 2097152);
  cast4_bf16_kernel<<<dim3(512, 4), dim3(256), 0, stream>>>(wq, wk, wv, wo, wqb, 1048576);

  gemm_qkv_kernel<<<dim3(16, 32, 3), dim3(256), 0, stream>>>(xb, wqb, wkb, wvb, Qb, Kb, Vt);
  attn_kernel<<<dim3(32, 16), dim3(256), 0, stream>>>(Qb, Kb, Vt, Ab);
  gemm_out_kernel<<<dim3(16, 32), dim3(256), 0, stream>>>(Ab, wob, out);
}

// Round 3
// 376.132 us; speedup vs baseline: 1.2801x; 1.1096x over previous
//
#include <hip/hip_runtime.h>
#include <stdint.h>
#include <stddef.h>

#define DIMN 2048
#define NH 16
#define HD 128
#define SEQ 2048
#define WIN 128   // mask: j - i > 128 is masked

typedef __attribute__((ext_vector_type(4))) float f32x4;
typedef __attribute__((ext_vector_type(8))) short bf16x8;
typedef __attribute__((ext_vector_type(4))) int i32x4;

#define AS1 __attribute__((address_space(1)))
#define AS3 __attribute__((address_space(3)))

__device__ __forceinline__ unsigned short f2bf(float f) {
  union { float f; unsigned u; } v; v.f = f;
  unsigned r = v.u + 0x7FFFu + ((v.u >> 16) & 1u);  // round-to-nearest-even
  return (unsigned short)(r >> 16);
}

// ---------------- cast f32 -> bf16 ----------------
__global__ void cast_bf16_kernel(const float* __restrict__ src,
                                 unsigned short* __restrict__ dst, int n4) {
  int i = blockIdx.x * blockDim.x + threadIdx.x;
  const int stride = gridDim.x * blockDim.x;
  for (; i < n4; i += stride) {
    float4 v = ((const float4*)src)[i];
    ushort4 o;
    o.x = f2bf(v.x); o.y = f2bf(v.y); o.z = f2bf(v.z); o.w = f2bf(v.w);
    ((ushort4*)dst)[i] = o;
  }
}

// fused cast of the 4 weight matrices (dst regions contiguous in ws)
__global__ void cast4_bf16_kernel(const float* __restrict__ s0, const float* __restrict__ s1,
                                  const float* __restrict__ s2, const float* __restrict__ s3,
                                  unsigned short* __restrict__ dst, int n4) {
  const float* s = (blockIdx.y == 0) ? s0 : (blockIdx.y == 1) ? s1 : (blockIdx.y == 2) ? s2 : s3;
  unsigned short* d = dst + (size_t)blockIdx.y * 4194304;
  int i = blockIdx.x * blockDim.x + threadIdx.x;
  const int stride = gridDim.x * blockDim.x;
  for (; i < n4; i += stride) {
    float4 v = ((const float4*)s)[i];
    ushort4 o;
    o.x = f2bf(v.x); o.y = f2bf(v.y); o.z = f2bf(v.z); o.w = f2bf(v.w);
    ((ushort4*)d)[i] = o;
  }
}

// ---------------- GEMM mainloop, m97-style ----------------
// C(128x128) = A x B^T (both row-major MxK / NxK), bf16, f32 acc.
// BK=64. Staging via global_load_lds width=16 (linear LDS dest, rule #21:
// the XOR slot-swizzle is applied to the per-lane GLOBAL source address and
// to the ds_read address; LDS rows are 128B = exactly 32 banks, so banks
// depend only on the swizzled slot -> reads spread like contiguous = free).
__device__ __forceinline__ void gemm_mainloop_g128(
    const unsigned short* __restrict__ A, const unsigned short* __restrict__ B,
    int m0, int n0, unsigned short* As, unsigned short* Bs, f32x4 acc[4][4]) {
  const int t = threadIdx.x, lane = t & 63, wid = t >> 6;
  const int c = lane & 15, g = lane >> 4;
  const int wr = wid >> 1, wc = wid & 1;

  // staging geometry: wave w stages rows [w*32, w*32+32) of each tile,
  // 4 chunks of 8 rows; lane l covers row (l>>3), slot (l&7) of the chunk.
  const int srow = wid * 32 + (lane >> 3);          // chunk base row (+(i*8))
  const int gslot = (lane & 7) ^ (lane >> 3);       // pre-swizzled global slot
                                                    // ((srow+8i)&7 == lane>>3)
  const unsigned short* ga = A + (size_t)(m0 + srow) * DIMN + gslot * 8;
  const unsigned short* gb = B + (size_t)(n0 + srow) * DIMN + gslot * 8;
  unsigned short* la = As + (size_t)(wid * 32) * 64;  // wave-uniform LDS base
  unsigned short* lb = Bs + (size_t)(wid * 32) * 64;

  const int swc = c & 7;  // read-side swizzle key (row&7 == c&7 for frag rows)

  for (int k0 = 0; k0 < DIMN; k0 += 64) {
    __syncthreads();  // previous K-tile's readers done
#pragma unroll
    for (int i = 0; i < 4; ++i) {
      __builtin_amdgcn_global_load_lds(
          (const AS1 unsigned*)(ga + (size_t)i * 8 * DIMN + k0),
          (AS3 unsigned*)(la + i * 8 * 64), 16, 0, 0);
      __builtin_amdgcn_global_load_lds(
          (const AS1 unsigned*)(gb + (size_t)i * 8 * DIMN + k0),
          (AS3 unsigned*)(lb + i * 8 * 64), 16, 0, 0);
    }
    __syncthreads();  // implicit vmcnt(0) drain -> LDS tile valid
#pragma unroll
    for (int kk = 0; kk < 2; ++kk) {
      bf16x8 af[4], bfv[4];
#pragma unroll
      for (int mi = 0; mi < 4; ++mi)
        af[mi] = *(const bf16x8*)&As[(wr * 64 + mi * 16 + c) * 64 +
                                     (((kk * 4 + g) ^ swc) * 8)];
#pragma unroll
      for (int ni = 0; ni < 4; ++ni)
        bfv[ni] = *(const bf16x8*)&Bs[(wc * 64 + ni * 16 + c) * 64 +
                                      (((kk * 4 + g) ^ swc) * 8)];
#pragma unroll
      for (int mi = 0; mi < 4; ++mi)
#pragma unroll
        for (int ni = 0; ni < 4; ++ni)
          acc[mi][ni] = __builtin_amdgcn_mfma_f32_16x16x32_bf16(
              af[mi], bfv[ni], acc[mi][ni], 0, 0, 0);
    }
  }
}

// ---------------- QKV projection (z: 0=Q, 1=K, 2=V-transposed) ----------------
__global__ __launch_bounds__(256, 3) void gemm_qkv_kernel(
    const unsigned short* __restrict__ Xb,
    const unsigned short* __restrict__ Wq,
    const unsigned short* __restrict__ Wk,
    const unsigned short* __restrict__ Wv,
    unsigned short* __restrict__ Qb,
    unsigned short* __restrict__ Kb,
    unsigned short* __restrict__ Vt) {
  __shared__ __attribute__((aligned(16))) unsigned short As[128 * 64];
  __shared__ __attribute__((aligned(16))) unsigned short Bs[128 * 64];
  const int z = blockIdx.z;
  const unsigned short* W = (z == 0) ? Wq : (z == 1) ? Wk : Wv;
  const int m0 = blockIdx.y * 128, n0 = blockIdx.x * 128;

  f32x4 acc[4][4];
  const f32x4 zv = {0.f, 0.f, 0.f, 0.f};
#pragma unroll
  for (int i = 0; i < 4; ++i)
#pragma unroll
    for (int j = 0; j < 4; ++j) acc[i][j] = zv;

  gemm_mainloop_g128(Xb, W, m0, n0, As, Bs, acc);

  const int lane = threadIdx.x & 63, wid = threadIdx.x >> 6;
  const int c = lane & 15, g = lane >> 4;
  const int wr = wid >> 1, wc = wid & 1;
  unsigned short* Out01 = (z == 0) ? Qb : Kb;
#pragma unroll
  for (int mi = 0; mi < 4; ++mi) {
#pragma unroll
    for (int ni = 0; ni < 4; ++ni) {
      const int mrow = m0 + wr * 64 + mi * 16 + g * 4;  // m = b*SEQ + s
      const int ncol = n0 + wc * 64 + ni * 16 + c;      // n = h*HD + d
      const int h = ncol >> 7, d = ncol & 127;
      const int b = mrow >> 11, s = mrow & 2047;
      if (z < 2) {
#pragma unroll
        for (int j = 0; j < 4; ++j)
          Out01[((size_t)(b * NH + h) * SEQ + s + j) * HD + d] =
              f2bf(acc[mi][ni][j]);
      } else {
        ushort4 pk;
        pk.x = f2bf(acc[mi][ni][0]); pk.y = f2bf(acc[mi][ni][1]);
        pk.z = f2bf(acc[mi][ni][2]); pk.w = f2bf(acc[mi][ni][3]);
        *(ushort4*)&Vt[((size_t)(b * NH + h) * HD + d) * SEQ + s] = pk;
      }
    }
  }
}

// ---------------- output projection: f32 out ----------------
__global__ __launch_bounds__(256, 3) void gemm_out_kernel(
    const unsigned short* __restrict__ Ab,
    const unsigned short* __restrict__ Wo,
    float* __restrict__ Cf) {
  __shared__ __attribute__((aligned(16))) unsigned short As[128 * 64];
  __shared__ __attribute__((aligned(16))) unsigned short Bs[128 * 64];
  const int m0 = blockIdx.y * 128, n0 = blockIdx.x * 128;

  f32x4 acc[4][4];
  const f32x4 zv = {0.f, 0.f, 0.f, 0.f};
#pragma unroll
  for (int i = 0; i < 4; ++i)
#pragma unroll
    for (int j = 0; j < 4; ++j) acc[i][j] = zv;

  gemm_mainloop_g128(Ab, Wo, m0, n0, As, Bs, acc);

  const int lane = threadIdx.x & 63, wid = threadIdx.x >> 6;
  const int c = lane & 15, g = lane >> 4;
  const int wr = wid >> 1, wc = wid & 1;
#pragma unroll
  for (int mi = 0; mi < 4; ++mi) {
#pragma unroll
    for (int ni = 0; ni < 4; ++ni) {
      const int mrow = m0 + wr * 64 + mi * 16 + g * 4;
      const int ncol = n0 + wc * 64 + ni * 16 + c;
#pragma unroll
      for (int j = 0; j < 4; ++j)
        Cf[(size_t)(mrow + j) * DIMN + ncol] = acc[mi][ni][j];
    }
  }
}

// ---------------- flash attention ----------------
// 128 q-rows per block (4 waves x 32 rows), KV tile = 64.
// K[64][128], V^T[128][64], P[4][32][64] in LDS, XOR-slot-swizzled (free).
// Grid: (x=bh=32, y) with y->qt remap so co-resident blocks (b, b+256)
// pair qt with 15-qt: per-CU work balanced (~37 KV-tiles each).
__global__ __launch_bounds__(256, 2) void attn_kernel(
    const unsigned short* __restrict__ Qg,
    const unsigned short* __restrict__ Kg,
    const unsigned short* __restrict__ Vtg,
    unsigned short* __restrict__ Og) {
  __shared__ __attribute__((aligned(16))) unsigned short Ks[64 * 128];
  __shared__ __attribute__((aligned(16))) unsigned short Vs[128 * 64];
  __shared__ __attribute__((aligned(16))) unsigned short Ps[4 * 32 * 64];

  const int bh = blockIdx.x;
  const int yy = blockIdx.y;
  const int qt = (yy < 8) ? yy : 23 - yy;  // qt(y) + qt(y+8) == 15
  const int q0 = qt * 128;
  const int t = threadIdx.x, wid = t >> 6, lane = t & 63;
  const int c = lane & 15, g = lane >> 4;
  const int swc = c & 7;  // swizzle key for reads (row&7 == c&7 for our rows)

  const unsigned short* Kbh = Kg + (size_t)bh * SEQ * HD;
  const unsigned short* Vbh = Vtg + (size_t)bh * HD * SEQ;

  // Q fragments: rows q0 + wid*32 + mi*16 + c ; k = kk*32 + g*8
  bf16x8 qf[2][4];
#pragma unroll
  for (int mi = 0; mi < 2; ++mi) {
    const unsigned short* qb =
        Qg + ((size_t)bh * SEQ + q0 + wid * 32 + mi * 16 + c) * HD + g * 8;
#pragma unroll
    for (int kk = 0; kk < 4; ++kk) qf[mi][kk] = *(const bf16x8*)(qb + kk * 32);
  }

  f32x4 o[2][8];
  const f32x4 zv = {0.f, 0.f, 0.f, 0.f};
#pragma unroll
  for (int mi = 0; mi < 2; ++mi)
#pragma unroll
    for (int ni = 0; ni < 8; ++ni) o[mi][ni] = zv;
  float M[2][4], L[2][4];
#pragma unroll
  for (int mi = 0; mi < 2; ++mi)
#pragma unroll
    for (int j = 0; j < 4; ++j) { M[mi][j] = -1e30f; L[mi][j] = 0.f; }

  const int ntA = (q0 + 256) >> 6;
  const int nt = (ntA < (SEQ >> 6)) ? ntA : (SEQ >> 6);
  const float kl2e = 0.08838834764831845f * 1.4426950408889634f;  // scale*log2(e)

  // staging geometry (per thread, loop-invariant)
  const int kswz = (t & 15) ^ ((t >> 4) & 7);
  const int vswz = (t & 7) ^ ((t >> 3) & 7);
  const int kgo = (t >> 4) * HD + (t & 15) * 8;            // K global offset within tile
  const int klo = (t >> 4) * 128 + kswz * 8;               // K LDS offset
  const int vlo = (t >> 3) * 64 + vswz * 8;                // V LDS offset
  const size_t vgo = (size_t)(t >> 3) * SEQ + (t & 7) * 8; // V global offset

  i32x4 kc[4], vc[4];
#pragma unroll
  for (int r = 0; r < 4; ++r) {  // prologue: tile 0
    kc[r] = *(const i32x4*)(Kbh + (size_t)r * 16 * HD + kgo);
    vc[r] = *(const i32x4*)(Vbh + (size_t)r * 32 * SEQ + vgo);
  }

  for (int tt = 0; tt < nt; ++tt) {
    const int j0 = tt * 64;
    __syncthreads();  // previous tile's LDS readers done
#pragma unroll
    for (int r = 0; r < 4; ++r) {
      *(i32x4*)&Ks[r * 2048 + klo] = kc[r];
      *(i32x4*)&Vs[r * 2048 + vlo] = vc[r];
    }
    __syncthreads();
    if (tt + 1 < nt) {  // prefetch next tile (latency hides under compute)
      const int j1 = j0 + 64;
#pragma unroll
      for (int r = 0; r < 4; ++r) {
        kc[r] = *(const i32x4*)(Kbh + (size_t)(j1 + r * 16) * HD + kgo);
        vc[r] = *(const i32x4*)(Vbh + (size_t)r * 32 * SEQ + j1 + vgo);
      }
    }

    // QK^T: 32 rows x 64 cols per wave; sc[mi][ni]: rows mi*16+4g+j, col 16ni+c
    f32x4 sc[2][4];
#pragma unroll
    for (int mi = 0; mi < 2; ++mi)
#pragma unroll
      for (int ni = 0; ni < 4; ++ni) sc[mi][ni] = zv;
    __builtin_amdgcn_s_setprio(1);
#pragma unroll
    for (int kk = 0; kk < 4; ++kk) {
#pragma unroll
      for (int ni = 0; ni < 4; ++ni) {
        const bf16x8 kf =
            *(const bf16x8*)&Ks[(ni * 16 + c) * 128 + ((kk * 4 + g) ^ swc) * 8];
        sc[0][ni] = __builtin_amdgcn_mfma_f32_16x16x32_bf16(qf[0][kk], kf, sc[0][ni], 0, 0, 0);
        sc[1][ni] = __builtin_amdgcn_mfma_f32_16x16x32_bf16(qf[1][kk], kf, sc[1][ni], 0, 0, 0);
      }
    }
    __builtin_amdgcn_s_setprio(0);

    // masking: only tiles with j0 >= q0+128 can contain masked elements
    if (j0 - q0 >= 128) {
#pragma unroll
      for (int mi = 0; mi < 2; ++mi)
#pragma unroll
        for (int ni = 0; ni < 4; ++ni) {
          const int jg = j0 + ni * 16 + c;
#pragma unroll
          for (int j = 0; j < 4; ++j) {
            const int ig = q0 + wid * 32 + mi * 16 + g * 4 + j;
            if (jg > ig + WIN) sc[mi][ni][j] = -3.0e38f;
          }
        }
    }

    // row maxima (rows live in 16-lane groups sharing g; xor<16 stays in group)
    float tmax[2][4], dmax = -3.0e38f;
#pragma unroll
    for (int mi = 0; mi < 2; ++mi)
#pragma unroll
      for (int j = 0; j < 4; ++j) {
        float mx = fmaxf(fmaxf(sc[mi][0][j], sc[mi][1][j]),
                         fmaxf(sc[mi][2][j], sc[mi][3][j]));
        mx = fmaxf(mx, __shfl_xor(mx, 1));
        mx = fmaxf(mx, __shfl_xor(mx, 2));
        mx = fmaxf(mx, __shfl_xor(mx, 4));
        mx = fmaxf(mx, __shfl_xor(mx, 8));
        tmax[mi][j] = mx;
        dmax = fmaxf(dmax, mx - M[mi][j]);
      }
    // defer-max (T13): rescale only when tile max exceeds running max by >64
    // unscaled logits (64*scale*log2e = 8.2 -> P <= 2^8.2, safe in bf16/f32)
    if (__any(dmax > 64.f)) {
#pragma unroll
      for (int mi = 0; mi < 2; ++mi)
#pragma unroll
        for (int j = 0; j < 4; ++j) {
          const float nm = fmaxf(M[mi][j], tmax[mi][j]);
          const float al = __builtin_amdgcn_exp2f((M[mi][j] - nm) * kl2e);
          M[mi][j] = nm;
          L[mi][j] *= al;
#pragma unroll
          for (int ni = 0; ni < 8; ++ni) o[mi][ni][j] *= al;
        }
    }

    // P = exp(sc - M), bf16, swizzled into per-wave LDS; accumulate row sums
    float rs[2][4] = {{0.f, 0.f, 0.f, 0.f}, {0.f, 0.f, 0.f, 0.f}};
#pragma unroll
    for (int mi = 0; mi < 2; ++mi)
#pragma unroll
      for (int ni = 0; ni < 4; ++ni)
#pragma unroll
        for (int j = 0; j < 4; ++j) {
          const float p = __builtin_amdgcn_exp2f((sc[mi][ni][j] - M[mi][j]) * kl2e);
          rs[mi][j] += p;
          const int prow = mi * 16 + g * 4 + j;
          Ps[wid * 2048 + prow * 64 + ((2 * ni + (c >> 3)) ^ (prow & 7)) * 8 + (c & 7)] =
              f2bf(p);
        }
#pragma unroll
    for (int mi = 0; mi < 2; ++mi)
#pragma unroll
      for (int j = 0; j < 4; ++j) {
        float s = rs[mi][j];
        s += __shfl_xor(s, 1);
        s += __shfl_xor(s, 2);
        s += __shfl_xor(s, 4);
        s += __shfl_xor(s, 8);
        L[mi][j] += s;
      }

    // PV: P(32x64) x V^T ; per-wave Ps, no barrier needed (same-wave write/read)
    __builtin_amdgcn_s_setprio(1);
#pragma unroll
    for (int kk2 = 0; kk2 < 2; ++kk2) {
      bf16x8 pf[2];
#pragma unroll
      for (int mi = 0; mi < 2; ++mi)
        pf[mi] = *(const bf16x8*)&Ps[wid * 2048 + (mi * 16 + c) * 64 +
                                     ((kk2 * 4 + g) ^ swc) * 8];
#pragma unroll
      for (int ni = 0; ni < 8; ++ni) {
        const bf16x8 vf =
            *(const bf16x8*)&Vs[(ni * 16 + c) * 64 + ((kk2 * 4 + g) ^ swc) * 8];
        o[0][ni] = __builtin_amdgcn_mfma_f32_16x16x32_bf16(pf[0], vf, o[0][ni], 0, 0, 0);
        o[1][ni] = __builtin_amdgcn_mfma_f32_16x16x32_bf16(pf[1], vf, o[1][ni], 0, 0, 0);
      }
    }
    __builtin_amdgcn_s_setprio(0);
  }

  // normalize + store attn output as (B*S, DIM) bf16 rows (GEMM2 A-operand)
  const int b = bh >> 4, h = bh & 15;
#pragma unroll
  for (int mi = 0; mi < 2; ++mi)
#pragma unroll
    for (int j = 0; j < 4; ++j) {
      const float inv = 1.0f / L[mi][j];
      const int s = q0 + wid * 32 + mi * 16 + g * 4 + j;
      unsigned short* orow = Og + (size_t)(b * SEQ + s) * DIMN + h * HD;
#pragma unroll
      for (int ni = 0; ni < 8; ++ni) orow[ni * 16 + c] = f2bf(o[mi][ni][j] * inv);
    }
}

// ---------------- launch ----------------
extern "C" void kernel_launch(void* const* d_in, const int* in_sizes, int n_in,
                              void* d_out, int out_size, void* d_ws, size_t ws_size,
                              hipStream_t stream) {
  (void)in_sizes; (void)n_in; (void)out_size; (void)ws_size;
  const float* x  = (const float*)d_in[0];
  const float* wq = (const float*)d_in[1];
  const float* wk = (const float*)d_in[2];
  const float* wv = (const float*)d_in[3];
  const float* wo = (const float*)d_in[4];
  float* out = (float*)d_out;

  // workspace layout (bf16 elems); total ~112 MB
  unsigned short* xb  = (unsigned short*)d_ws;          // 4096x2048
  unsigned short* wqb = xb  + (size_t)8388608;          // 2048x2048 each, contiguous
  unsigned short* wkb = wqb + (size_t)4194304;
  unsigned short* wvb = wkb + (size_t)4194304;
  unsigned short* wob = wvb + (size_t)4194304;
  unsigned short* Qb  = wob + (size_t)4194304;          // (B,H,S,D)
  unsigned short* Kb  = Qb  + (size_t)8388608;          // (B,H,S,D)
  unsigned short* Vt  = Kb  + (size_t)8388608;          // (B,H,D,S)
  unsigned short* Ab  = Vt  + (size_t)8388608;          // (B*S, DIM)

  cast_bf16_kernel<<<dim3(1024), dim3(256), 0, stream>>>(x, xb, 2097152);
  cast4_bf16_kernel<<<dim3(512, 4), dim3(256), 0, stream>>>(wq, wk, wv, wo, wqb, 1048576);

  gemm_qkv_kernel<<<dim3(16, 32, 3), dim3(256), 0, stream>>>(xb, wqb, wkb, wvb, Qb, Kb, Vt);
  attn_kernel<<<dim3(32, 16), dim3(256), 0, stream>>>(Qb, Kb, Vt, Ab);
  gemm_out_kernel<<<dim3(16, 32), dim3(256), 0, stream>>>(Ab, wob, out);
}